// Round 8
// baseline (232.797 us; speedup 1.0000x reference)
//
#include <hip/hip_runtime.h>
#include <math.h>

#define N_TOK 8192
#define DM 1024
#define NE 8
#define HE 512
#define NPAIR 16384
#define MAXMB 264      // max M-blocks: sum_e ceil(cnt_e/64) <= 256 + 8

#define BM 64
#define OSTR 136       // gemm1 epilogue LDS row stride (elems)
#define OSTR2 264      // gemm2 epilogue LDS row stride (elems)

#define GSTR 1028      // gate LDS row stride (fp32 elems)

typedef __bf16 bf16x8 __attribute__((ext_vector_type(8)));
typedef float f32x4 __attribute__((ext_vector_type(4)));

#define GLOBAL_AS __attribute__((address_space(1)))
#define LDS_AS    __attribute__((address_space(3)))

__device__ __forceinline__ void gl_lds16(const void* g, void* lds) {
    __builtin_amdgcn_global_load_lds((const GLOBAL_AS unsigned int*)g,
                                     (LDS_AS unsigned int*)lds, 16, 0, 0);
}

__device__ __forceinline__ unsigned short f2bf(float f) {
    unsigned int u = __float_as_uint(f);
    u += 0x7fffu + ((u >> 16) & 1u);   // RNE; inputs finite
    return (unsigned short)(u >> 16);
}

__device__ __forceinline__ float gelu_exact(float v) {
    return 0.5f * v * (1.0f + erff(v * 0.70710678118654752440f));
}

__device__ __forceinline__ double shfl_xor_dbl(double v, int m) {
    long long l = __double_as_longlong(v);
    int lo = (int)(l & 0xffffffffll);
    int hi = (int)(l >> 32);
    lo = __shfl_xor(lo, m, 64);
    hi = __shfl_xor(hi, m, 64);
    return __longlong_as_double(((long long)hi << 32) | (unsigned long long)(unsigned int)lo);
}

// ---- fused: gate (softmax+top2, fp64 acc) + x->bf16 cast + w1/w2 transpose ----
// blocks [0,2048): gate+cast (4 tokens each). blocks [2048,4096): transpose.
__global__ __launch_bounds__(256) void prep_kernel(
        const float* __restrict__ x, const float* __restrict__ gw,
        const float* __restrict__ w1, const float* __restrict__ w2,
        unsigned short* __restrict__ xb,
        unsigned short* __restrict__ w1t, unsigned short* __restrict__ w2t,
        float* __restrict__ w_tok, int* __restrict__ e_sel) {
    __shared__ float smf[NE * GSTR];   // 32,896 B (transpose uses first 16,640 B)
    int bid = blockIdx.x;
    int tid = threadIdx.x;

    if (bid >= 2048) {
        // ---------------- transpose+cast role ----------------
        int t = bid - 2048;
        int z = t >> 7;            // 0..15
        int idx = t & 127;
        int bx = idx & 7, by = idx >> 3;
        const float* src; unsigned short* dst; int R, C, c0, r0;
        if (z < 8) {
            src = w1 + (size_t)z * DM * HE; dst = w1t + (size_t)z * DM * HE;
            R = DM; C = HE; c0 = bx * 64; r0 = by * 64;
        } else {
            int e = z - 8;
            src = w2 + (size_t)e * HE * DM; dst = w2t + (size_t)e * HE * DM;
            R = HE; C = DM; c0 = by * 64; r0 = bx * 64;
        }
        float (*tile)[65] = (float(*)[65])smf;
        int tc = tid & 63, tg = tid >> 6;
        #pragma unroll
        for (int i = 0; i < 16; i++) {
            int r = tg * 16 + i;
            tile[r][tc] = src[(size_t)(r0 + r) * C + (c0 + tc)];
        }
        __syncthreads();
        #pragma unroll
        for (int i = 0; i < 16; i++) {
            int r = tg * 16 + i;
            dst[(size_t)(c0 + r) * R + (r0 + tc)] = f2bf(tile[tc][r]);
        }
        return;
    }

    // ---------------- gate + cast role ----------------
    float* gls = smf;
    for (int v = tid; v < 2048; v += 256) {
        float4 g4 = ((const float4*)gw)[v];
        int idx = v * 4;
        int d = idx >> 3;
        int e0 = idx & 7;   // 0 or 4
        gls[(e0    ) * GSTR + d] = g4.x;
        gls[(e0 + 1) * GSTR + d] = g4.y;
        gls[(e0 + 2) * GSTR + d] = g4.z;
        gls[(e0 + 3) * GSTR + d] = g4.w;
    }
    __syncthreads();

    int n = bid * 4 + (tid >> 6);
    int lane = tid & 63;
    const float4* xr = (const float4*)(x + (size_t)n * DM);
    ushort4* xw = (ushort4*)(xb + (size_t)n * DM);

    double s[NE];
    #pragma unroll
    for (int e = 0; e < NE; e++) s[e] = 0.0;

    #pragma unroll
    for (int i = 0; i < 4; i++) {
        float4 x4 = xr[i * 64 + lane];
        ushort4 o;
        o.x = f2bf(x4.x); o.y = f2bf(x4.y); o.z = f2bf(x4.z); o.w = f2bf(x4.w);
        xw[i * 64 + lane] = o;
        int d = (i * 64 + lane) * 4;
        #pragma unroll
        for (int e = 0; e < NE; e++) {
            float4 g4 = *(const float4*)(&gls[e * GSTR + d]);
            s[e] += (double)x4.x * (double)g4.x + (double)x4.y * (double)g4.y
                  + (double)x4.z * (double)g4.z + (double)x4.w * (double)g4.w;
        }
    }
    #pragma unroll
    for (int e = 0; e < NE; e++) {
        for (int off = 32; off > 0; off >>= 1)
            s[e] += shfl_xor_dbl(s[e], off);
    }
    if (lane == 0) {
        double m = s[0];
        for (int e = 1; e < NE; e++) if (s[e] > m) m = s[e];
        double sum = 0.0;
        for (int e = 0; e < NE; e++) sum += exp(s[e] - m);
        int i1 = 0; double v1 = s[0];
        for (int e = 1; e < NE; e++) if (s[e] > v1) { v1 = s[e]; i1 = e; }
        int i2 = -1; double v2 = -1e300;
        for (int e = 0; e < NE; e++) if (e != i1 && s[e] > v2) { v2 = s[e]; i2 = e; }
        w_tok[n] = (float)((exp(v1 - m) + exp(v2 - m)) / sum);
        e_sel[2 * n]     = i1;
        e_sel[2 * n + 1] = i2;
    }
}

// ------ routing: histogram + scan + scatter + per-M-block tables, ONE block ------
__global__ __launch_bounds__(1024) void route_kernel(
        const int* __restrict__ e_sel, int* __restrict__ cnt, int* __restrict__ offs,
        int* __restrict__ pair_tok, int* __restrict__ slotmap,
        int* __restrict__ mb_e, int* __restrict__ mb_base, int* __restrict__ n_mb) {
    __shared__ int wbin[16][NE];     // per-wave bins -> later per-wave cursors
    __shared__ int wstart[16][NE];
    __shared__ int etot[NE], eoffs[NE], bofs[NE];
    int tid = threadIdx.x;
    int w = tid >> 6, l = tid & 63;
    if (l < NE) wbin[w][l] = 0;
    __syncthreads();

    int sel[16];
    #pragma unroll
    for (int k = 0; k < 16; k++) {
        sel[k] = e_sel[tid * 16 + k];
        atomicAdd(&wbin[w][sel[k]], 1);
    }
    __syncthreads();

    if (tid < NE) {
        int t = 0;
        for (int ww = 0; ww < 16; ww++) t += wbin[ww][tid];
        etot[tid] = t;
    }
    __syncthreads();
    if (tid == 0) {
        int a = 0, b = 0;
        for (int e = 0; e < NE; e++) {
            eoffs[e] = a; a += etot[e];
            bofs[e] = b;  b += (etot[e] + BM - 1) / BM;
        }
        n_mb[0] = b;
    }
    __syncthreads();
    if (tid < NE) {
        cnt[tid] = etot[tid];
        offs[tid] = eoffs[tid];
        int r = eoffs[tid];
        for (int ww = 0; ww < 16; ww++) { wstart[ww][tid] = r; r += wbin[ww][tid]; }
        int nb = (etot[tid] + BM - 1) / BM;
        int b0 = bofs[tid];
        for (int b = 0; b < nb; b++) {
            mb_e[b0 + b] = tid;
            mb_base[b0 + b] = eoffs[tid] + b * BM;
        }
    }
    __syncthreads();
    if (l < NE) wbin[w][l] = wstart[w][l];   // reuse as cursors
    __syncthreads();

    #pragma unroll
    for (int k = 0; k < 16; k++) {
        int i = tid * 16 + k;
        int slot = atomicAdd(&wbin[w][sel[k]], 1);
        pair_tok[slot] = i >> 1;
        slotmap[i] = slot;
    }
}

// ---------------- GEMM1: h = gelu(x_gathered @ w1[e] + b1[e]) ----------------
// 64x128 tile, BK=128 (32 MFMA per barrier period), 48 KB LDS, 3 blocks/CU.
// LDS rows are 256 B = two 128 B halves; the proven XOR-8 swizzle applies
// within each half: LDS slot q of row r holds source group q^(r&7).
__global__ __launch_bounds__(256, 3) void gemm1_kernel(
        const unsigned short* __restrict__ xb,      // [N_TOK][DM] bf16
        const unsigned short* __restrict__ w1t,     // [E][HE][DM] bf16 (B^T layout)
        const float* __restrict__ b1,               // [E][HE]
        const int* __restrict__ pair_tok,
        const int* __restrict__ cnt, const int* __restrict__ offs,
        const int* __restrict__ mb_e, const int* __restrict__ mb_base,
        const int* __restrict__ n_mb,
        unsigned short* __restrict__ hbuf) {        // [NPAIR][HE] bf16
    int mb = blockIdx.y;
    if (mb >= n_mb[0]) return;
    int e = mb_e[mb];
    int sbase = mb_base[mb];
    int vlim = offs[e] + cnt[e];
    int n0 = blockIdx.x * 128;

    __shared__ __align__(16) unsigned short smem[(64 + 128) * 128];   // 48 KB
    char* As = (char*)smem;            // 16 KB: 64 rows x 256 B
    char* Bs = (char*)smem + 16384;    // 32 KB: 128 rows x 256 B

    int tid = threadIdx.x;
    int lane = tid & 63;
    int w = tid >> 6;
    int wu = __builtin_amdgcn_readfirstlane(w);
    int r16 = lane >> 4;           // row within 4-row chunk
    int s7  = lane & 7;            // sub-slot within half
    int hb  = ((lane >> 3) & 1) * 128;   // half byte offset

    const char* aptr[4];
    #pragma unroll
    for (int j = 0; j < 4; j++) {
        int rl = w * 16 + j * 4 + r16;
        int slot = sbase + rl;
        int t = pair_tok[slot < vlim ? slot : vlim - 1];
        int sub = s7 ^ (rl & 7);
        aptr[j] = (const char*)xb + (size_t)t * (DM * 2) + hb + sub * 16;
    }
    const char* bptr[8];
    #pragma unroll
    for (int j = 0; j < 8; j++) {
        int rl = w * 32 + j * 4 + r16;
        int sub = s7 ^ (rl & 7);
        bptr[j] = (const char*)w1t + ((size_t)e * HE + n0 + rl) * (DM * 2) + hb + sub * 16;
    }

    int wm = (w & 1) * 32;
    int wn = (w >> 1) * 64;
    int fr = lane & 15;
    int fq = lane >> 4;

    f32x4 acc[2][4];
    #pragma unroll
    for (int i = 0; i < 2; i++)
        #pragma unroll
        for (int j = 0; j < 4; j++)
            acc[i][j] = (f32x4){0.f, 0.f, 0.f, 0.f};

    for (int k0 = 0; k0 < DM; k0 += 128) {
        int kb = k0 * 2;
        #pragma unroll
        for (int j = 0; j < 4; j++)
            gl_lds16(aptr[j] + kb, As + wu * 4096 + j * 1024);
        #pragma unroll
        for (int j = 0; j < 8; j++)
            gl_lds16(bptr[j] + kb, Bs + wu * 8192 + j * 1024);
        __syncthreads();   // drains vmcnt: LDS tiles ready
        #pragma unroll
        for (int kk = 0; kk < 4; kk++) {
            int off = (kk >> 1) * 128 + ((((kk & 1) * 4 + fq) ^ (fr & 7)) << 4);
            bf16x8 af[2];
            #pragma unroll
            for (int i = 0; i < 2; i++)
                af[i] = *(const bf16x8*)(As + (wm + i * 16 + fr) * 256 + off);
            #pragma unroll
            for (int j = 0; j < 4; j++) {
                bf16x8 bfv = *(const bf16x8*)(Bs + (wn + j * 16 + fr) * 256 + off);
                #pragma unroll
                for (int i = 0; i < 2; i++)
                    acc[i][j] = __builtin_amdgcn_mfma_f32_16x16x32_bf16(af[i], bfv, acc[i][j], 0, 0, 0);
            }
        }
        __syncthreads();   // all waves done reading before next stage overwrites
    }

    // ---- epilogue: stage to LDS (stride OSTR), then coalesced 64 B stores ----
    unsigned short* ot = smem;   // 64*136*2 = 17,408 B
    #pragma unroll
    for (int j = 0; j < 4; j++) {
        int nl = wn + j * 16 + fr;
        float bias = b1[e * HE + n0 + nl];
        #pragma unroll
        for (int i = 0; i < 2; i++) {
            #pragma unroll
            for (int r = 0; r < 4; r++) {
                int mm = wm + i * 16 + fq * 4 + r;
                ot[mm * OSTR + nl] = f2bf(gelu_exact(acc[i][j][r] + bias));
            }
        }
    }
    __syncthreads();
    int row = tid >> 2;
    int c0 = (tid & 3) * 32;
    if (sbase + row < vlim) {
        const uint4* sp = (const uint4*)(ot + row * OSTR + c0);
        uint4* dp = (uint4*)(hbuf + (size_t)(sbase + row) * HE + n0 + c0);
        dp[0] = sp[0]; dp[1] = sp[1]; dp[2] = sp[2]; dp[3] = sp[3];
    }
}

// -------- GEMM2: ybuf[slot] = h @ w2[e] + b2[e]  (bf16; w_tok applied in combine) --------
// 64x256 tile (A reused 4x not 8x), BK=64, 40 KB LDS, 4 blocks/CU.
__global__ __launch_bounds__(256, 4) void gemm2_kernel(
        const unsigned short* __restrict__ hbuf,    // [NPAIR][HE] bf16
        const unsigned short* __restrict__ w2t,     // [E][DM][HE] bf16 (B^T layout)
        const float* __restrict__ b2,               // [E][DM]
        const int* __restrict__ pair_tok,
        const int* __restrict__ cnt, const int* __restrict__ offs,
        const int* __restrict__ mb_e, const int* __restrict__ mb_base,
        const int* __restrict__ n_mb,
        unsigned short* __restrict__ ybuf) {        // [NPAIR][DM] bf16
    int mb = blockIdx.y;
    if (mb >= n_mb[0]) return;
    int e = mb_e[mb];
    int sbase = mb_base[mb];
    int vlim = offs[e] + cnt[e];
    int n0 = blockIdx.x * 256;

    __shared__ __align__(16) unsigned short smem[(64 + 256) * 64];   // 40,960 B exactly
    char* As = (char*)smem;            //  8 KB: 64 rows x 128 B
    char* Bs = (char*)smem + 8192;     // 32 KB: 256 rows x 128 B

    int tid = threadIdx.x;
    int lane = tid & 63;
    int w = tid >> 6;
    int wu = __builtin_amdgcn_readfirstlane(w);
    int l3 = lane >> 3, l7 = lane & 7;
    int g = l7 ^ l3;

    const char* aptr[2];
    #pragma unroll
    for (int j = 0; j < 2; j++) {
        int rl = w * 16 + j * 8 + l3;
        int slot = sbase + rl;
        int cs = (slot < vlim) ? slot : vlim - 1;   // clamp OOB rows
        aptr[j] = (const char*)hbuf + (size_t)cs * (HE * 2) + g * 16;
    }
    const char* bptr[8];
    #pragma unroll
    for (int j = 0; j < 8; j++) {
        int rl = w * 64 + j * 8 + l3;
        bptr[j] = (const char*)w2t + ((size_t)e * DM + n0 + rl) * (HE * 2) + g * 16;
    }

    int wm = (w & 1) * 32;
    int wn = (w >> 1) * 128;
    int fr = lane & 15;
    int fq = lane >> 4;

    f32x4 acc[2][8];
    #pragma unroll
    for (int i = 0; i < 2; i++)
        #pragma unroll
        for (int j = 0; j < 8; j++)
            acc[i][j] = (f32x4){0.f, 0.f, 0.f, 0.f};

    for (int k0 = 0; k0 < HE; k0 += 64) {
        int kb = k0 * 2;
        #pragma unroll
        for (int j = 0; j < 2; j++)
            gl_lds16(aptr[j] + kb, As + wu * 2048 + j * 1024);
        #pragma unroll
        for (int j = 0; j < 8; j++)
            gl_lds16(bptr[j] + kb, Bs + wu * 8192 + j * 1024);
        __syncthreads();
        #pragma unroll
        for (int kk2 = 0; kk2 < 2; kk2++) {
            int sw = ((kk2 * 4 + fq) ^ (fr & 7)) << 4;
            bf16x8 af[2];
            #pragma unroll
            for (int i = 0; i < 2; i++)
                af[i] = *(const bf16x8*)(As + (wm + i * 16 + fr) * 128 + sw);
            #pragma unroll
            for (int j = 0; j < 8; j++) {
                bf16x8 bfv = *(const bf16x8*)(Bs + (wn + j * 16 + fr) * 128 + sw);
                #pragma unroll
                for (int i = 0; i < 2; i++)
                    acc[i][j] = __builtin_amdgcn_mfma_f32_16x16x32_bf16(af[i], bfv, acc[i][j], 0, 0, 0);
            }
        }
        __syncthreads();
    }

    // ---- epilogue: stage to LDS (stride OSTR2), two coalesced half-passes ----
    unsigned short* ot = smem;   // 64*264*2 = 33,792 B <= 40,960
    #pragma unroll
    for (int j = 0; j < 8; j++) {
        int nl = wn + j * 16 + fr;
        float bias = b2[e * DM + n0 + nl];
        #pragma unroll
        for (int i = 0; i < 2; i++) {
            #pragma unroll
            for (int r = 0; r < 4; r++) {
                int mm = wm + i * 16 + fq * 4 + r;
                ot[mm * OSTR2 + nl] = f2bf(acc[i][j][r] + bias);
            }
        }
    }
    __syncthreads();
    int row = tid >> 2;
    bool live = (sbase + row < vlim);
    #pragma unroll
    for (int p = 0; p < 2; p++) {
        int c0 = p * 128 + (tid & 3) * 32;
        if (live) {
            const uint4* sp = (const uint4*)(ot + row * OSTR2 + c0);
            uint4* dp = (uint4*)(ybuf + (size_t)(sbase + row) * DM + n0 + c0);
            dp[0] = sp[0]; dp[1] = sp[1]; dp[2] = sp[2]; dp[3] = sp[3];
        }
    }
}

// ---------------- combine: out[n] = w_tok[n] * (yb[slot1] + yb[slot2]) ----------------
__device__ __forceinline__ float2 bfpair(unsigned int u) {
    float2 f;
    f.x = __uint_as_float(u << 16);
    f.y = __uint_as_float(u & 0xffff0000u);
    return f;
}

__global__ void combine_kernel(const unsigned short* __restrict__ yb,
                               const int* __restrict__ slotmap,
                               const float* __restrict__ w_tok,
                               float* __restrict__ out) {
    int i = blockIdx.x * 256 + threadIdx.x;   // N_TOK*DM/8 threads
    int n = i >> 7;                            // 128 8-elem groups per token
    int c = (i & 127) * 8;
    int s1 = slotmap[2 * n];
    int s2 = slotmap[2 * n + 1];
    float wt = w_tok[n];
    uint4 a = *(const uint4*)(&yb[(size_t)s1 * DM + c]);
    uint4 b = *(const uint4*)(&yb[(size_t)s2 * DM + c]);
    float2 ax = bfpair(a.x), ay = bfpair(a.y), az = bfpair(a.z), aw = bfpair(a.w);
    float2 bx = bfpair(b.x), by = bfpair(b.y), bz = bfpair(b.z), bw = bfpair(b.w);
    float4 o0, o1;
    o0.x = wt * (ax.x + bx.x); o0.y = wt * (ax.y + bx.y);
    o0.z = wt * (ay.x + by.x); o0.w = wt * (ay.y + by.y);
    o1.x = wt * (az.x + bz.x); o1.y = wt * (az.y + bz.y);
    o1.z = wt * (aw.x + bw.x); o1.w = wt * (aw.y + bw.y);
    float4* dp = (float4*)(out + (size_t)n * DM + c);
    dp[0] = o0; dp[1] = o1;
}

extern "C" void kernel_launch(void* const* d_in, const int* in_sizes, int n_in,
                              void* d_out, int out_size, void* d_ws, size_t ws_size,
                              hipStream_t stream) {
    const float* x  = (const float*)d_in[0];
    const float* gw = (const float*)d_in[1];
    const float* w1 = (const float*)d_in[2];
    const float* b1 = (const float*)d_in[3];
    const float* w2 = (const float*)d_in[4];
    const float* b2 = (const float*)d_in[5];
    float* out = (float*)d_out;

    char* ws = (char*)d_ws;
    // ws layout (bytes), total ~59 MB.
    // ybuf (33.5 MB) overlays xb + w1t: both dead by the time gemm2 runs.
    unsigned short* ybuf = (unsigned short*)(ws);              // 33,554,432 [NPAIR][DM] bf16
    unsigned short* xb   = (unsigned short*)(ws);              // 16,777,216 (dead after gemm1)
    unsigned short* w1t  = (unsigned short*)(ws + 16777216);   //  8,388,608 (dead after gemm1)
    unsigned short* w2t  = (unsigned short*)(ws + 33554432);   //  8,388,608  [e][d][h]
    unsigned short* hbuf = (unsigned short*)(ws + 41943040);   // 16,777,216  [NPAIR][HE]
    float* w_tok         = (float*)(ws + 58720256);            //     32,768
    int*   e_sel         = (int*)(ws + 58753024);              //     65,536
    int*   slotmap       = (int*)(ws + 58818560);              //     65,536
    int*   cnt           = (int*)(ws + 58884096);              //         32
    int*   offs          = (int*)(ws + 58884128);              //         32
    int*   pair_tok      = (int*)(ws + 58884224);              //     65,536
    int*   mb_e          = (int*)(ws + 58949760);              //      1,088
    int*   mb_base       = (int*)(ws + 58950848);              //      1,088
    int*   n_mb          = (int*)(ws + 58951936);              //          4

    prep_kernel<<<4096, 256, 0, stream>>>(x, gw, w1, w2, xb, w1t, w2t, w_tok, e_sel);
    route_kernel<<<1, 1024, 0, stream>>>(e_sel, cnt, offs, pair_tok, slotmap,
                                         mb_e, mb_base, n_mb);
    gemm1_kernel<<<dim3(HE / 128, MAXMB), 256, 0, stream>>>(
        xb, w1t, b1, pair_tok, cnt, offs, mb_e, mb_base, n_mb, hbuf);
    gemm2_kernel<<<dim3(DM / 256, MAXMB), 256, 0, stream>>>(
        hbuf, w2t, b2, pair_tok, cnt, offs, mb_e, mb_base, n_mb, ybuf);
    combine_kernel<<<(N_TOK * DM / 8) / 256, 256, 0, stream>>>(ybuf, slotmap, w_tok, out);
}